// Round 7
// baseline (152.497 us; speedup 1.0000x reference)
//
#include <hip/hip_runtime.h>
#include <hip/hip_bf16.h>

#define TWOPI_OVER_B 0.049087385212340517f  // 2*pi/128

typedef __attribute__((ext_vector_type(8))) short bf16x8;
typedef __attribute__((ext_vector_type(4))) float f32x4;

static __device__ __forceinline__ unsigned short f2bf(float f) {
    __hip_bfloat16 h = __float2bfloat16(f);
    return *reinterpret_cast<unsigned short*>(&h);
}
static __device__ __forceinline__ unsigned long long pack4(float a, float b, float c, float d) {
    return (unsigned long long)f2bf(a) | ((unsigned long long)f2bf(b) << 16)
         | ((unsigned long long)f2bf(c) << 32) | ((unsigned long long)f2bf(d) << 48);
}

// ---------------------------------------------------------------------------
// Prep (validated rounds 4-5): blocks 0..79 build fragB + fragCi; blocks
// 80..95 build BmatT[k][o2][j2] via MFMA DFT with table-built local fragB.
__global__ __launch_bounds__(256) void k_prep(const float* __restrict__ W,
                                              unsigned short* __restrict__ fragB,
                                              unsigned short* __restrict__ fragCi,
                                              unsigned short* __restrict__ BmatT) {
    __shared__ char smem[73984];
    __shared__ float tbl[256];
    int tid = threadIdx.x;

    if (blockIdx.x < 80) {
        int i = blockIdx.x * 256 + tid;
        if (i < 18432) {                       // fragB: ((c*4+kb)*64 + l)*8 + e
            int e = i & 7, l2 = (i >> 3) & 63, kb = (i >> 9) & 3, c = i >> 11;
            int kr = c * 16 + (l2 & 15);
            int t  = kb * 32 + (l2 >> 4) * 8 + e;
            float v = 0.f;
            if (kr < 65)       v =  cosf(TWOPI_OVER_B * (float)((kr * t) & 127));
            else if (kr < 130) v = -sinf(TWOPI_OVER_B * (float)(((kr - 65) * t) & 127));
            fragB[i] = f2bf(v);
        }
        if (i < 20480) {                       // fragCi: ((c*5+kb)*64 + l)*8 + e
            int e = i & 7, l2 = (i >> 3) & 63;
            int ckb = i >> 9; int kb = ckb % 5, c = ckb / 5;
            int kr = kb * 32 + (l2 >> 4) * 8 + e;
            int t  = c * 16 + (l2 & 15);
            float v = 0.f;
            if (kr < 65)       v =  cosf(TWOPI_OVER_B * (float)((kr * t) & 127));
            else if (kr < 130) v = -sinf(TWOPI_OVER_B * (float)(((kr - 65) * t) & 127));
            fragCi[i] = f2bf(v);
        }
        return;
    }

    int bw = blockIdx.x - 80;                  // 0..15, 2 o's each
    unsigned long long* xs8 = (unsigned long long*)smem;
    float* Yl = (float*)smem;                  // [0,37120)
    unsigned short* fB = (unsigned short*)(smem + 37120);  // 36864B

    for (int i = tid; i < 128; i += 256) {
        float s, c;
        sincosf(TWOPI_OVER_B * (float)i, &s, &c);
        tbl[i] = c; tbl[128 + i] = s;
    }
    __syncthreads();

    for (int i = tid; i < 18432; i += 256) {   // local fragB via table
        int e = i & 7, l2 = (i >> 3) & 63, kb = (i >> 9) & 3, c = i >> 11;
        int kr = c * 16 + (l2 & 15);
        int t  = kb * 32 + (l2 >> 4) * 8 + e;
        float v = 0.f;
        if (kr < 65)       v =  tbl[(kr * t) & 127];
        else if (kr < 130) v = -tbl[128 + (((kr - 65) * t) & 127)];
        fB[i] = f2bf(v);
    }
    #pragma unroll
    for (int it = 0; it < 8; ++it) {           // 64 rows x 128 = 2048 float4
        int f  = tid + it * 256;
        float4 wa = ((const float4*)W)[(size_t)bw * 2048 + f];
        int rl = f >> 5;
        int t0 = (f & 31) * 4;
        int byte = (rl * 256 + t0 * 2) ^ ((rl & 7) << 4);
        xs8[byte >> 3] = pack4(wa.x, wa.y, wa.z, wa.w);
    }
    __syncthreads();

    int l = tid & 63, w = tid >> 6;
    int rl_a = w * 16 + (l & 15);
    int coff = (l >> 4) * 16;
    bf16x8 a[4];
    #pragma unroll
    for (int kb = 0; kb < 4; ++kb) {
        int byte = (rl_a * 256 + kb * 64 + coff) ^ ((rl_a & 7) << 4);
        a[kb] = *(const bf16x8*)(smem + byte);
    }
    __syncthreads();                           // xs dead; Yl overwrites

    f32x4 acc[9];
    #pragma unroll
    for (int c = 0; c < 9; ++c) acc[c] = (f32x4)0.f;
    #pragma unroll
    for (int c = 0; c < 9; ++c)
        #pragma unroll
        for (int kb = 0; kb < 4; ++kb)
            acc[c] = __builtin_amdgcn_mfma_f32_16x16x32_bf16(a[kb], ((const bf16x8*)fB)[(c * 4 + kb) * 64 + l], acc[c], 0, 0, 0);

    int rowd = w * 16 + (l >> 4) * 4;
    int cold = l & 15;
    #pragma unroll
    for (int c = 0; c < 9; ++c)
        #pragma unroll
        for (int r = 0; r < 4; ++r)
            Yl[(rowd + r) * 145 + c * 16 + cold] = acc[c][r];
    __syncthreads();

    int o0 = bw * 2;
    for (int c2 = tid; c2 < 4160; c2 += 256) {
        int k = c2 >> 6, sub = c2 & 63;
        int oo = sub >> 5, h = (sub >> 4) & 1, t = sub & 15;
        int j0 = t * 4;
        float sc = (k == 0 || k == 64) ? (1.f / 128.f) : (2.f / 128.f);
        int col; float sgn;
        if (j0 < 32) { col = h ? 65 + k : k;  sgn = h ? -sc : sc; }
        else         { col = h ? k : 65 + k;  sgn = sc; }
        int rlb = oo * 32 + (j0 & 31);
        unsigned long long pk = pack4(sgn * Yl[(rlb + 0) * 145 + col], sgn * Yl[(rlb + 1) * 145 + col],
                                      sgn * Yl[(rlb + 2) * 145 + col], sgn * Yl[(rlb + 3) * 145 + col]);
        int o2 = h * 32 + o0 + oo;
        *(unsigned long long*)(BmatT + ((size_t)k * 64 + o2) * 64 + j0) = pk;
    }
}

// ---------------------------------------------------------------------------
#define SMEM_BYTES 20480   // max phase: idft ys (fdft xs 16384, einsum 16384)

// Stage A (round-3 body + direct-store epilogue, mapping validated r4/r5):
static __device__ __forceinline__ void fdft_body(char* smem, int tid, int np,
        const float* __restrict__ x, const float* __restrict__ D,
        const bf16x8* __restrict__ fragB, unsigned short* __restrict__ Xb) {
    unsigned long long* xs8 = (unsigned long long*)smem;
    int n0 = np * 2;
    #pragma unroll
    for (int it = 0; it < 8; ++it) {
        int f  = tid + it * 256;
        int nn = f >> 10;
        int f4 = f & 1023;
        float4 xa = ((const float4*)(x + (size_t)(n0 + nn) * 4096))[f4];
        float4 da = ((const float4*)D)[f4];
        int rl = nn * 32 + (f4 >> 5);
        int t0 = (f4 & 31) * 4;
        int byte = (rl * 256 + t0 * 2) ^ ((rl & 7) << 4);
        xs8[byte >> 3] = pack4(xa.x * da.x, xa.y * da.y, xa.z * da.z, xa.w * da.w);
    }
    __syncthreads();

    int l = tid & 63, w = tid >> 6;
    int lr = l & 15, lq = l >> 4;
    int rl_a = w * 16 + lr;
    bf16x8 a[4];
    #pragma unroll
    for (int kb = 0; kb < 4; ++kb) {
        int byte = (rl_a * 256 + kb * 64 + lq * 16) ^ ((rl_a & 7) << 4);
        a[kb] = *(const bf16x8*)(smem + byte);
    }
    f32x4 acc[9];
    #pragma unroll
    for (int c = 0; c < 9; ++c) acc[c] = (f32x4)0.f;
    #pragma unroll
    for (int c = 0; c < 9; ++c)
        #pragma unroll
        for (int kb = 0; kb < 4; ++kb)
            acc[c] = __builtin_amdgcn_mfma_f32_16x16x32_bf16(a[kb], fragB[(c * 4 + kb) * 64 + l], acc[c], 0, 0, 0);

    // direct store: row = w*16+lq*4+r -> (nn, j), col = c*16+lr -> (k, re/im)
    int rowbase = w * 16 + lq * 4;
    int nn = rowbase >> 5, j0 = rowbase & 31;
    #pragma unroll
    for (int c = 0; c < 9; ++c) {
        int col = c * 16 + lr;
        if (col < 130) {
            int k   = (col < 65) ? col : col - 65;
            int off = (col < 65) ? 0 : 32;
            *(unsigned long long*)(Xb + ((size_t)k * 1024 + n0 + nn) * 64 + off + j0)
                = pack4(acc[c][0], acc[c][1], acc[c][2], acc[c][3]);
        }
    }
}

// Stage B (round-3 body, verbatim; u = k*8 + mt):
static __device__ __forceinline__ void einsum_body(char* lds, int tid, int u,
        const unsigned short* __restrict__ Xb, const unsigned short* __restrict__ BmatT,
        unsigned short* __restrict__ Y2) {
    int l = tid & 63, w = tid >> 6;
    int k = u >> 3, mt = u & 7;
    int m0 = mt * 128 + w * 32;
    int lr = l & 15, lq = l >> 4;
    __syncthreads();

    bf16x8 a[2][2], b[4][2];
    #pragma unroll
    for (int rf = 0; rf < 2; ++rf)
        #pragma unroll
        for (int kb = 0; kb < 2; ++kb)
            a[rf][kb] = *(const bf16x8*)(Xb + ((size_t)k * 1024 + m0 + rf * 16 + lr) * 64 + kb * 32 + lq * 8);
    #pragma unroll
    for (int cf = 0; cf < 4; ++cf)
        #pragma unroll
        for (int kb = 0; kb < 2; ++kb)
            b[cf][kb] = *(const bf16x8*)(BmatT + ((size_t)k * 64 + cf * 16 + lr) * 64 + kb * 32 + lq * 8);

    f32x4 acc[2][4];
    #pragma unroll
    for (int rf = 0; rf < 2; ++rf)
        #pragma unroll
        for (int cf = 0; cf < 4; ++cf) acc[rf][cf] = (f32x4)0.f;
    #pragma unroll
    for (int rf = 0; rf < 2; ++rf)
        #pragma unroll
        for (int cf = 0; cf < 4; ++cf) {
            acc[rf][cf] = __builtin_amdgcn_mfma_f32_16x16x32_bf16(a[rf][0], b[cf][0], acc[rf][cf], 0, 0, 0);
            acc[rf][cf] = __builtin_amdgcn_mfma_f32_16x16x32_bf16(a[rf][1], b[cf][1], acc[rf][cf], 0, 0, 0);
        }

    #pragma unroll
    for (int rf = 0; rf < 2; ++rf)
        #pragma unroll
        for (int cf = 0; cf < 4; ++cf)
            #pragma unroll
            for (int rr = 0; rr < 4; ++rr) {
                int row = rf * 16 + lq * 4 + rr;
                int col = cf * 16 + lr;
                int byte = w * 4096 + ((row * 128 + col * 2) ^ ((row & 7) << 4));
                *(unsigned short*)(lds + byte) = f2bf(acc[rf][cf][rr]);
            }
    __syncthreads();
    #pragma unroll
    for (int i = 0; i < 4; ++i) {
        int row = i * 8 + (l >> 3);
        int byte = w * 4096 + ((row * 128 + (l & 7) * 16) ^ ((row & 7) << 4));
        bf16x8 v = *(const bf16x8*)(lds + byte);
        *(bf16x8*)(Y2 + ((size_t)k * 1024 + m0 + row) * 64 + (l & 7) * 8) = v;
    }
}

// Stage C (round-3 body, verbatim; bi = block index):
static __device__ __forceinline__ void idft_body(char* smem, int tid, int bi,
        const unsigned short* __restrict__ Y2, const bf16x8* __restrict__ fragCi,
        float* __restrict__ out) {
    int row0 = bi * 64;
    int n0 = bi * 2;
    __syncthreads();

    for (int i = tid; i < 1920; i += 256) {
        int rl = i / 30, cp = 130 + i % 30;
        int byte = (rl * 320 + cp * 2) ^ ((rl & 7) << 4);
        *(unsigned short*)(smem + byte) = 0;
    }
    for (int c2 = tid; c2 < 2080; c2 += 256) {
        int k = c2 >> 5, sub = c2 & 31, nn = sub >> 4, t = sub & 15;
        unsigned long long v = *(const unsigned long long*)(Y2 + ((size_t)k * 1024 + n0 + nn) * 64 + t * 4);
        int o2_0 = t * 4;
        int col = (o2_0 < 32) ? k : 65 + k;
        int r0 = nn * 32 + (o2_0 & 31);
        #pragma unroll
        for (int i = 0; i < 4; ++i) {
            int rl = r0 + i;
            int byte = (rl * 320 + col * 2) ^ ((rl & 7) << 4);
            *(unsigned short*)(smem + byte) = (unsigned short)(v >> (16 * i));
        }
    }
    __syncthreads();

    int l = tid & 63, w = tid >> 6;
    int rl_a = w * 16 + (l & 15);
    int coff = (l >> 4) * 16;
    bf16x8 a[5];
    #pragma unroll
    for (int kb = 0; kb < 5; ++kb) {
        int byte = (rl_a * 320 + kb * 64 + coff) ^ ((rl_a & 7) << 4);
        a[kb] = *(const bf16x8*)(smem + byte);
    }
    f32x4 acc[8];
    #pragma unroll
    for (int c = 0; c < 8; ++c) acc[c] = (f32x4)0.f;
    #pragma unroll
    for (int c = 0; c < 8; ++c)
        #pragma unroll
        for (int kb = 0; kb < 5; ++kb)
            acc[c] = __builtin_amdgcn_mfma_f32_16x16x32_bf16(a[kb], fragCi[(c * 5 + kb) * 64 + l], acc[c], 0, 0, 0);

    int rowd = row0 + w * 16 + (l >> 4) * 4;
    int cold = l & 15;
    #pragma unroll
    for (int c = 0; c < 8; ++c)
        #pragma unroll
        for (int r = 0; r < 4; ++r)
            out[(size_t)(rowd + r) * 128 + c * 16 + cold] = acc[c][r];
}

// ---------------------------------------------------------------------------
// Software grid barrier: monotonic counter, phase p waits for count >= p*512.
static __device__ __forceinline__ void gbar(unsigned* bar, unsigned target) {
    __syncthreads();
    if (threadIdx.x == 0) {
        __hip_atomic_fetch_add(bar, 1u, __ATOMIC_RELEASE, __HIP_MEMORY_SCOPE_AGENT);
        while (__hip_atomic_load(bar, __ATOMIC_ACQUIRE, __HIP_MEMORY_SCOPE_AGENT) < target)
            __builtin_amdgcn_s_sleep(2);
    }
    __syncthreads();
}

// Persistent kernel: fdft | bar | einsum | bar | idft.
// LDS 20480 -> 7 blocks/CU capacity; launch_bounds(256,2) -> >=2 blocks/CU
// guaranteed resident; grid 512 = 2/CU needed -> all co-resident, no deadlock.
__global__ __launch_bounds__(256, 2) void k_persist(const float* __restrict__ x,
                                                    const float* __restrict__ D,
                                                    float* __restrict__ out,
                                                    const bf16x8* __restrict__ fragB,
                                                    const bf16x8* __restrict__ fragCi,
                                                    const unsigned short* __restrict__ BmatT,
                                                    unsigned short* __restrict__ Xb,
                                                    unsigned short* __restrict__ Y2,
                                                    unsigned* __restrict__ bar) {
    __shared__ char smem[SMEM_BYTES];
    int tid = threadIdx.x;
    int bi  = blockIdx.x;

    fdft_body(smem, tid, bi, x, D, fragB, Xb);
    gbar(bar, 512);

    einsum_body(smem, tid, bi, Xb, BmatT, Y2);
    if (bi < 8) einsum_body(smem, tid, 512 + bi, Xb, BmatT, Y2);
    gbar(bar, 1024);

    idft_body(smem, tid, bi, Y2, fragCi, out);
}

// ---------------------------------------------------------------------------
extern "C" void kernel_launch(void* const* d_in, const int* in_sizes, int n_in,
                              void* d_out, int out_size, void* d_ws, size_t ws_size,
                              hipStream_t stream) {
    const float* x = (const float*)d_in[0];
    const float* W = (const float*)d_in[1];
    const float* D = (const float*)d_in[2];
    float* out = (float*)d_out;
    float* ws  = (float*)d_ws;

    unsigned short* BmatT  = (unsigned short*)ws;               // 266240 bf16
    unsigned short* Xb     = (unsigned short*)(ws + 133120);    // 4259840 bf16
    unsigned short* Y2     = (unsigned short*)(ws + 2263040);   // 4259840 bf16
    unsigned short* fragB  = (unsigned short*)(ws + 4392960);   // 18432 bf16
    unsigned short* fragCi = fragB + 18432;                     // 20480 bf16
    unsigned*       bar    = (unsigned*)((char*)d_ws + 17649728);

    hipMemsetAsync(bar, 0, 64, stream);
    k_prep   <<<96, 256, 0, stream>>>(W, fragB, fragCi, BmatT);
    k_persist<<<512, 256, 0, stream>>>(x, D, out, (const bf16x8*)fragB,
                                       (const bf16x8*)fragCi, BmatT, Xb, Y2, bar);
}

// Round 8
// 49.699 us; speedup vs baseline: 3.0684x; 3.0684x over previous
//
#include <hip/hip_runtime.h>
#include <hip/hip_bf16.h>

#define TWOPI_OVER_B 0.049087385212340517f  // 2*pi/128

typedef __attribute__((ext_vector_type(8))) short bf16x8;
typedef __attribute__((ext_vector_type(4))) float f32x4;

static __device__ __forceinline__ unsigned short f2bf(float f) {
    __hip_bfloat16 h = __float2bfloat16(f);
    return *reinterpret_cast<unsigned short*>(&h);
}
static __device__ __forceinline__ unsigned long long pack4(float a, float b, float c, float d) {
    return (unsigned long long)f2bf(a) | ((unsigned long long)f2bf(b) << 16)
         | ((unsigned long long)f2bf(c) << 32) | ((unsigned long long)f2bf(d) << 48);
}

// ---------------------------------------------------------------------------
// Prep (validated R4/R5/R7): blocks 0..79 build fragB + fragCi; blocks
// 80..95 build BmatT[k][o2][j2] via MFMA DFT with table-built local fragB.
__global__ __launch_bounds__(256) void k_prep(const float* __restrict__ W,
                                              unsigned short* __restrict__ fragB,
                                              unsigned short* __restrict__ fragCi,
                                              unsigned short* __restrict__ BmatT) {
    __shared__ char smem[73984];
    __shared__ float tbl[256];
    int tid = threadIdx.x;

    if (blockIdx.x < 80) {
        int i = blockIdx.x * 256 + tid;
        if (i < 18432) {                       // fragB: ((c*4+kb)*64 + l)*8 + e
            int e = i & 7, l2 = (i >> 3) & 63, kb = (i >> 9) & 3, c = i >> 11;
            int kr = c * 16 + (l2 & 15);
            int t  = kb * 32 + (l2 >> 4) * 8 + e;
            float v = 0.f;
            if (kr < 65)       v =  cosf(TWOPI_OVER_B * (float)((kr * t) & 127));
            else if (kr < 130) v = -sinf(TWOPI_OVER_B * (float)(((kr - 65) * t) & 127));
            fragB[i] = f2bf(v);
        }
        if (i < 20480) {                       // fragCi: ((c*5+kb)*64 + l)*8 + e
            int e = i & 7, l2 = (i >> 3) & 63;
            int ckb = i >> 9; int kb = ckb % 5, c = ckb / 5;
            int kr = kb * 32 + (l2 >> 4) * 8 + e;
            int t  = c * 16 + (l2 & 15);
            float v = 0.f;
            if (kr < 65)       v =  cosf(TWOPI_OVER_B * (float)((kr * t) & 127));
            else if (kr < 130) v = -sinf(TWOPI_OVER_B * (float)(((kr - 65) * t) & 127));
            fragCi[i] = f2bf(v);
        }
        return;
    }

    int bw = blockIdx.x - 80;                  // 0..15, 2 o's each
    unsigned long long* xs8 = (unsigned long long*)smem;
    float* Yl = (float*)smem;                  // [0,37120)
    unsigned short* fB = (unsigned short*)(smem + 37120);  // 36864B

    for (int i = tid; i < 128; i += 256) {
        float s, c;
        sincosf(TWOPI_OVER_B * (float)i, &s, &c);
        tbl[i] = c; tbl[128 + i] = s;
    }
    __syncthreads();

    for (int i = tid; i < 18432; i += 256) {   // local fragB via table
        int e = i & 7, l2 = (i >> 3) & 63, kb = (i >> 9) & 3, c = i >> 11;
        int kr = c * 16 + (l2 & 15);
        int t  = kb * 32 + (l2 >> 4) * 8 + e;
        float v = 0.f;
        if (kr < 65)       v =  tbl[(kr * t) & 127];
        else if (kr < 130) v = -tbl[128 + (((kr - 65) * t) & 127)];
        fB[i] = f2bf(v);
    }
    #pragma unroll
    for (int it = 0; it < 8; ++it) {           // 64 rows x 128 = 2048 float4
        int f  = tid + it * 256;
        float4 wa = ((const float4*)W)[(size_t)bw * 2048 + f];
        int rl = f >> 5;
        int t0 = (f & 31) * 4;
        int byte = (rl * 256 + t0 * 2) ^ ((rl & 7) << 4);
        xs8[byte >> 3] = pack4(wa.x, wa.y, wa.z, wa.w);
    }
    __syncthreads();

    int l = tid & 63, w = tid >> 6;
    int rl_a = w * 16 + (l & 15);
    int coff = (l >> 4) * 16;
    bf16x8 a[4];
    #pragma unroll
    for (int kb = 0; kb < 4; ++kb) {
        int byte = (rl_a * 256 + kb * 64 + coff) ^ ((rl_a & 7) << 4);
        a[kb] = *(const bf16x8*)(smem + byte);
    }
    __syncthreads();                           // xs dead; Yl overwrites

    f32x4 acc[9];
    #pragma unroll
    for (int c = 0; c < 9; ++c) acc[c] = (f32x4)0.f;
    #pragma unroll
    for (int c = 0; c < 9; ++c)
        #pragma unroll
        for (int kb = 0; kb < 4; ++kb)
            acc[c] = __builtin_amdgcn_mfma_f32_16x16x32_bf16(a[kb], ((const bf16x8*)fB)[(c * 4 + kb) * 64 + l], acc[c], 0, 0, 0);

    int rowd = w * 16 + (l >> 4) * 4;
    int cold = l & 15;
    #pragma unroll
    for (int c = 0; c < 9; ++c)
        #pragma unroll
        for (int r = 0; r < 4; ++r)
            Yl[(rowd + r) * 145 + c * 16 + cold] = acc[c][r];
    __syncthreads();

    int o0 = bw * 2;
    for (int c2 = tid; c2 < 4160; c2 += 256) {
        int k = c2 >> 6, sub = c2 & 63;
        int oo = sub >> 5, h = (sub >> 4) & 1, t = sub & 15;
        int j0 = t * 4;
        float sc = (k == 0 || k == 64) ? (1.f / 128.f) : (2.f / 128.f);
        int col; float sgn;
        if (j0 < 32) { col = h ? 65 + k : k;  sgn = h ? -sc : sc; }
        else         { col = h ? k : 65 + k;  sgn = sc; }
        int rlb = oo * 32 + (j0 & 31);
        unsigned long long pk = pack4(sgn * Yl[(rlb + 0) * 145 + col], sgn * Yl[(rlb + 1) * 145 + col],
                                      sgn * Yl[(rlb + 2) * 145 + col], sgn * Yl[(rlb + 3) * 145 + col]);
        int o2 = h * 32 + o0 + oo;
        *(unsigned long long*)(BmatT + ((size_t)k * 64 + o2) * 64 + j0) = pk;
    }
}

// ---------------------------------------------------------------------------
// Stage A (validated R7): DFT with direct-store epilogue -> Xb[k][n][j2]
__global__ __launch_bounds__(256) void k_fdft(const float* __restrict__ x,
                                              const float* __restrict__ D,
                                              const bf16x8* __restrict__ fragB,
                                              unsigned short* __restrict__ Xb) {
    __shared__ char smem[16384];
    unsigned long long* xs8 = (unsigned long long*)smem;
    int tid = threadIdx.x;
    int n0 = blockIdx.x * 2;

    #pragma unroll
    for (int it = 0; it < 8; ++it) {
        int f  = tid + it * 256;
        int nn = f >> 10;
        int f4 = f & 1023;
        float4 xa = ((const float4*)(x + (size_t)(n0 + nn) * 4096))[f4];
        float4 da = ((const float4*)D)[f4];
        int rl = nn * 32 + (f4 >> 5);
        int t0 = (f4 & 31) * 4;
        int byte = (rl * 256 + t0 * 2) ^ ((rl & 7) << 4);
        xs8[byte >> 3] = pack4(xa.x * da.x, xa.y * da.y, xa.z * da.z, xa.w * da.w);
    }
    __syncthreads();

    int l = tid & 63, w = tid >> 6;
    int lr = l & 15, lq = l >> 4;
    int rl_a = w * 16 + lr;
    bf16x8 a[4];
    #pragma unroll
    for (int kb = 0; kb < 4; ++kb) {
        int byte = (rl_a * 256 + kb * 64 + lq * 16) ^ ((rl_a & 7) << 4);
        a[kb] = *(const bf16x8*)(smem + byte);
    }
    f32x4 acc[9];
    #pragma unroll
    for (int c = 0; c < 9; ++c) acc[c] = (f32x4)0.f;
    #pragma unroll
    for (int c = 0; c < 9; ++c)
        #pragma unroll
        for (int kb = 0; kb < 4; ++kb)
            acc[c] = __builtin_amdgcn_mfma_f32_16x16x32_bf16(a[kb], fragB[(c * 4 + kb) * 64 + l], acc[c], 0, 0, 0);

    // direct store: row = w*16+lq*4+r -> (nn, j), col = c*16+lr -> (k, re/im)
    int rowbase = w * 16 + lq * 4;
    int nn = rowbase >> 5, j0 = rowbase & 31;
    #pragma unroll
    for (int c = 0; c < 9; ++c) {
        int col = c * 16 + lr;
        if (col < 130) {
            int k   = (col < 65) ? col : col - 65;
            int off = (col < 65) ? 0 : 32;
            *(unsigned long long*)(Xb + ((size_t)k * 1024 + n0 + nn) * 64 + off + j0)
                = pack4(acc[c][0], acc[c][1], acc[c][2], acc[c][3]);
        }
    }
}

// ---------------------------------------------------------------------------
// Stage B (validated R3/R7): per-k GEMM [1024x64]x[64x64] -> Y2[k][n][o2]
__global__ __launch_bounds__(256) void k_einsum(const unsigned short* __restrict__ Xb,
                                                const unsigned short* __restrict__ BmatT,
                                                unsigned short* __restrict__ Y2) {
    __shared__ char lds[16384];
    int tid = threadIdx.x, l = tid & 63, w = tid >> 6;
    int k = blockIdx.x >> 3, mt = blockIdx.x & 7;
    int m0 = mt * 128 + w * 32;
    int lr = l & 15, lq = l >> 4;

    bf16x8 a[2][2], b[4][2];
    #pragma unroll
    for (int rf = 0; rf < 2; ++rf)
        #pragma unroll
        for (int kb = 0; kb < 2; ++kb)
            a[rf][kb] = *(const bf16x8*)(Xb + ((size_t)k * 1024 + m0 + rf * 16 + lr) * 64 + kb * 32 + lq * 8);
    #pragma unroll
    for (int cf = 0; cf < 4; ++cf)
        #pragma unroll
        for (int kb = 0; kb < 2; ++kb)
            b[cf][kb] = *(const bf16x8*)(BmatT + ((size_t)k * 64 + cf * 16 + lr) * 64 + kb * 32 + lq * 8);

    f32x4 acc[2][4];
    #pragma unroll
    for (int rf = 0; rf < 2; ++rf)
        #pragma unroll
        for (int cf = 0; cf < 4; ++cf) acc[rf][cf] = (f32x4)0.f;
    #pragma unroll
    for (int rf = 0; rf < 2; ++rf)
        #pragma unroll
        for (int cf = 0; cf < 4; ++cf) {
            acc[rf][cf] = __builtin_amdgcn_mfma_f32_16x16x32_bf16(a[rf][0], b[cf][0], acc[rf][cf], 0, 0, 0);
            acc[rf][cf] = __builtin_amdgcn_mfma_f32_16x16x32_bf16(a[rf][1], b[cf][1], acc[rf][cf], 0, 0, 0);
        }

    #pragma unroll
    for (int rf = 0; rf < 2; ++rf)
        #pragma unroll
        for (int cf = 0; cf < 4; ++cf)
            #pragma unroll
            for (int rr = 0; rr < 4; ++rr) {
                int row = rf * 16 + lq * 4 + rr;
                int col = cf * 16 + lr;
                int byte = w * 4096 + ((row * 128 + col * 2) ^ ((row & 7) << 4));
                *(unsigned short*)(lds + byte) = f2bf(acc[rf][cf][rr]);
            }
    __syncthreads();
    #pragma unroll
    for (int i = 0; i < 4; ++i) {
        int row = i * 8 + (l >> 3);
        int byte = w * 4096 + ((row * 128 + (l & 7) * 16) ^ ((row & 7) << 4));
        bf16x8 v = *(const bf16x8*)(lds + byte);
        *(bf16x8*)(Y2 + ((size_t)k * 1024 + m0 + row) * 64 + (l & 7) * 8) = v;
    }
}

// ---------------------------------------------------------------------------
// Stage C (validated R3/R7): iDFT, rows=(n,o), K=160 pad
__global__ __launch_bounds__(256) void k_idft(const unsigned short* __restrict__ Y2,
                                              const bf16x8* __restrict__ fragCi,
                                              float* __restrict__ out) {
    __shared__ char smem[20480];            // ys[64][160] bf16, swizzled
    int tid = threadIdx.x;
    int row0 = blockIdx.x * 64;
    int n0 = blockIdx.x * 2;

    for (int i = tid; i < 1920; i += 256) {
        int rl = i / 30, cp = 130 + i % 30;
        int byte = (rl * 320 + cp * 2) ^ ((rl & 7) << 4);
        *(unsigned short*)(smem + byte) = 0;
    }
    for (int c2 = tid; c2 < 2080; c2 += 256) {
        int k = c2 >> 5, sub = c2 & 31, nn = sub >> 4, t = sub & 15;
        unsigned long long v = *(const unsigned long long*)(Y2 + ((size_t)k * 1024 + n0 + nn) * 64 + t * 4);
        int o2_0 = t * 4;
        int col = (o2_0 < 32) ? k : 65 + k;
        int r0 = nn * 32 + (o2_0 & 31);
        #pragma unroll
        for (int i = 0; i < 4; ++i) {
            int rl = r0 + i;
            int byte = (rl * 320 + col * 2) ^ ((rl & 7) << 4);
            *(unsigned short*)(smem + byte) = (unsigned short)(v >> (16 * i));
        }
    }
    __syncthreads();

    int l = tid & 63, w = tid >> 6;
    int rl_a = w * 16 + (l & 15);
    int coff = (l >> 4) * 16;
    bf16x8 a[5];
    #pragma unroll
    for (int kb = 0; kb < 5; ++kb) {
        int byte = (rl_a * 320 + kb * 64 + coff) ^ ((rl_a & 7) << 4);
        a[kb] = *(const bf16x8*)(smem + byte);
    }
    f32x4 acc[8];
    #pragma unroll
    for (int c = 0; c < 8; ++c) acc[c] = (f32x4)0.f;
    #pragma unroll
    for (int c = 0; c < 8; ++c)
        #pragma unroll
        for (int kb = 0; kb < 5; ++kb)
            acc[c] = __builtin_amdgcn_mfma_f32_16x16x32_bf16(a[kb], fragCi[(c * 5 + kb) * 64 + l], acc[c], 0, 0, 0);

    int rowd = row0 + w * 16 + (l >> 4) * 4;
    int cold = l & 15;
    #pragma unroll
    for (int c = 0; c < 8; ++c)
        #pragma unroll
        for (int r = 0; r < 4; ++r)
            out[(size_t)(rowd + r) * 128 + c * 16 + cold] = acc[c][r];
}

// ---------------------------------------------------------------------------
extern "C" void kernel_launch(void* const* d_in, const int* in_sizes, int n_in,
                              void* d_out, int out_size, void* d_ws, size_t ws_size,
                              hipStream_t stream) {
    const float* x = (const float*)d_in[0];
    const float* W = (const float*)d_in[1];
    const float* D = (const float*)d_in[2];
    float* out = (float*)d_out;
    float* ws  = (float*)d_ws;

    unsigned short* BmatT  = (unsigned short*)ws;               // 266240 bf16
    unsigned short* Xb     = (unsigned short*)(ws + 133120);    // 4259840 bf16
    unsigned short* Y2     = (unsigned short*)(ws + 2263040);   // 4259840 bf16
    unsigned short* fragB  = (unsigned short*)(ws + 4392960);   // 18432 bf16
    unsigned short* fragCi = fragB + 18432;                     // 20480 bf16

    k_prep  <<<96, 256, 0, stream>>>(W, fragB, fragCi, BmatT);
    k_fdft  <<<512, 256, 0, stream>>>(x, D, (const bf16x8*)fragB, Xb);
    k_einsum<<<520, 256, 0, stream>>>(Xb, BmatT, Y2);
    k_idft  <<<512, 256, 0, stream>>>(Y2, (const bf16x8*)fragCi, out);
}